// Round 5
// baseline (5808.319 us; speedup 1.0000x reference)
//
#include <hip/hip_runtime.h>
#include <cstdint>
#include <cstddef>

#define B_   256
#define T_   512
#define E_   128
#define H_   256
#define G3   768

typedef _Float16 f16x8 __attribute__((ext_vector_type(8)));
typedef _Float16 f16x4 __attribute__((ext_vector_type(4)));
typedef float    f32x4 __attribute__((ext_vector_type(4)));

__device__ __forceinline__ float sigm(float x) { return 1.f / (1.f + __expf(-x)); }
__device__ __forceinline__ float tanh_(float x) {
  x = fminf(15.f, fmaxf(-15.f, x));
  float e = __expf(2.f * x);
  return (e - 1.f) / (e + 1.f);
}
__device__ __forceinline__ f16x8 cvt8(float4 a, float4 b) {
  f16x8 r;
  r[0] = (_Float16)a.x; r[1] = (_Float16)a.y; r[2] = (_Float16)a.z; r[3] = (_Float16)a.w;
  r[4] = (_Float16)b.x; r[5] = (_Float16)b.y; r[6] = (_Float16)b.z; r[7] = (_Float16)b.w;
  return r;
}

// ---------------- prep: swizzle weights to MFMA fragment order (fp16), biases, zero HX ------
// WSW[dir][kc(12)][tile(48)][lane(64)][8] fp16. kc 0..7: W_hh (K=256), kc 8..11: W_ih (K=128).
// Fragment (A or B — identical layout): lane l supplies W[tile*16+(l&15)][k=(l>>4)*8+j], i.e. 8
// k-consecutive fp32 of the original row-major weights. Tiles 0..15=r, 16..31=z, 32..47=n.
// BIAS[dir][4][256]: 0: b_ih_r+b_hh_r, 1: b_ih_z+b_hh_z, 2: b_ih_n, 3: b_hh_n.
__global__ __launch_bounds__(256) void prep_kernel(
    const float* __restrict__ whhf, const float* __restrict__ whhb,
    const float* __restrict__ wihf, const float* __restrict__ wihb,
    const float* __restrict__ bihf, const float* __restrict__ bhhf,
    const float* __restrict__ bihb, const float* __restrict__ bhhb,
    _Float16* __restrict__ WSW, float* __restrict__ BIAS,
    unsigned int* __restrict__ HXz)
{
  int idx = blockIdx.x * 256 + threadIdx.x;
  if (idx < 73728) {                          // 2*12*48*64
    int lane = idx & 63;
    int tile = (idx >> 6) % 48;
    int kc   = (idx / 3072) % 12;
    int dir  = idx / 36864;
    int ncol = tile * 16 + (lane & 15);
    int quad = lane >> 4;
    const float* src;
    if (kc < 8) {
      const float* w = dir ? whhb : whhf;     // [768][256] row-major
      src = w + (size_t)ncol * H_ + kc * 32 + quad * 8;
    } else {
      const float* w = dir ? wihb : wihf;     // [768][128] row-major
      src = w + (size_t)ncol * E_ + (kc - 8) * 32 + quad * 8;
    }
    f16x8 v;
    #pragma unroll
    for (int j = 0; j < 8; ++j) v[j] = (_Float16)src[j];
    *(f16x8*)(WSW + (size_t)idx * 8) = v;
  } else if (idx < 73728 + 2048) {
    int i2 = idx - 73728;
    int d = i2 >> 10, kind = (i2 >> 8) & 3, j = i2 & 255;
    const float* bih = d ? bihb : bihf;
    const float* bhh = d ? bhhb : bhhf;
    float v;
    if      (kind == 0) v = bih[j] + bhh[j];
    else if (kind == 1) v = bih[H_ + j] + bhh[H_ + j];
    else if (kind == 2) v = bih[2 * H_ + j];
    else                v = bhh[2 * H_ + j];
    BIAS[d * 1024 + kind * 256 + j] = v;
  } else if (idx < 73728 + 2048 + 131072) {   // zero all of HX (h(0) = 0)
    HXz[idx - 75776] = 0u;
  }
}

// ------- rank rows by length (desc) + zero group counters (ws is re-poisoned each call) ------
__global__ void sort_kernel(const int* __restrict__ lens, int* __restrict__ order,
                            int* __restrict__ cnt)
{
  int i = threadIdx.x;                        // one block of 256
  for (int k = i; k < 1024; k += 256) cnt[k] = 0;
  int li = lens[i];
  int rank = 0;
  for (int k = 0; k < B_; ++k) {
    int lk = lens[k];
    rank += (lk > li) || (lk == li && k < i);
  }
  order[rank] = i;
}

// ---------------- barrier-free fused GRU scan ------------------------------------------------
// 64 blocks = 32 groups (2 dir x 16 chain-groups) x 2 sub-blocks; 16 waves per group.
// Operand swap: A = W (m=unit), B = h (n=chain) -> D[m=unit-sub][n=chain]: lane(lm,lq) holds
// units u0..u0+3 of chain lm. Store (8 B contiguous) to HX[g][parity][chain][unit] — which is
// exactly the next step's B-frag layout (h[chain][k=unit] k-contiguous). No LDS transpose,
// no in-loop __syncthreads.
// Sync: each wave, after its loads (of h(t)) and stores (of h(t+1)) complete, does ONE release
// atomic add on the group counter; each wave polls (acquire) counter >= 16*t before touching
// h(t). Release = s_waitcnt vmcnt(0) covers the whole wave's loads+stores; acquire emits
// buffer_inv so plain (L1-cached) h loads are fresh. Parity double-buffer + counter induction
// bound wave skew to <1 step -> reuse of buf[(t+1)&1] (last holding h(t-1)) is race-free.
__global__ __launch_bounds__(512, 2) void scan_kernel(
    const _Float16* __restrict__ WSW, const float* __restrict__ BIAS,
    const int* __restrict__ seqs, const float* __restrict__ embed,
    const int* __restrict__ lens, const int* __restrict__ order,
    _Float16* __restrict__ HX, int* __restrict__ CNT, float* __restrict__ hcat)
{
  __shared__ __align__(16) _Float16 wlds[8][12][64][8];  // x-part weight frags, 96 KB
  __shared__ int s_row[16], s_len[16];

  const int g = blockIdx.x & 31, sub = blockIdx.x >> 5;  // peer block = blockIdx ^ 32
  const int dir = g & 1, grp = g >> 1;
  const int tid = threadIdx.x;
  const int w = tid >> 6, lane = tid & 63, lm = lane & 15, lq = lane >> 4;
  const int wid = sub * 8 + w;                // global wave id in group: owns units [16wid,+16)

  if (tid < 16) { int r = order[grp * 16 + tid]; s_row[tid] = r; s_len[tid] = lens[r]; }

  // ---- stage x-part weight frags (kc 8..11, 3 gates) into this wave's private LDS region ----
  const _Float16* wsd = WSW + (size_t)dir * 294912 + (size_t)lane * 8;
  #pragma unroll
  for (int f = 0; f < 12; ++f) {              // f = gate*4 + kc'
    int kc = 8 + (f & 3), tile = (f >> 2) * 16 + wid;
    f16x8 v = *(const f16x8*)(wsd + (size_t)kc * 24576 + tile * 512);
    *(f16x8*)(&wlds[w][f][lane][0]) = v;      // own-wave write, own-wave read: no barrier needed
  }
  // ---- h-part weights -> registers (24 x f16x8 = 96 VGPR) ----
  f16x8 wh_r[8], wh_z[8], wh_n[8];
  #pragma unroll
  for (int kc = 0; kc < 8; ++kc) {
    wh_r[kc] = *(const f16x8*)(wsd + (size_t)kc * 24576 + (wid)      * 512);
    wh_z[kc] = *(const f16x8*)(wsd + (size_t)kc * 24576 + (16 + wid) * 512);
    wh_n[kc] = *(const f16x8*)(wsd + (size_t)kc * 24576 + (32 + wid) * 512);
  }

  const int u0 = 16 * wid + lq * 4;           // first of this lane's 4 owned units
  float4 b_r4  = *(const float4*)(BIAS + dir * 1024 +        u0);
  float4 b_z4  = *(const float4*)(BIAS + dir * 1024 + 256 +  u0);
  float4 b_nx4 = *(const float4*)(BIAS + dir * 1024 + 512 +  u0);
  float4 b_nh4 = *(const float4*)(BIAS + dir * 1024 + 768 +  u0);
  float br_[4] = {b_r4.x,  b_r4.y,  b_r4.z,  b_r4.w};
  float bz_[4] = {b_z4.x,  b_z4.y,  b_z4.z,  b_z4.w};
  float bx_[4] = {b_nx4.x, b_nx4.y, b_nx4.z, b_nx4.w};
  float bh_[4] = {b_nh4.x, b_nh4.y, b_nh4.z, b_nh4.w};

  __syncthreads();                            // s_row/s_len visible (only barrier in kernel)
  const int rowb = s_row[lm], len_l = s_len[lm];   // this lane's chain = lm
  int ml = 1;
  #pragma unroll
  for (int i = 0; i < 16; ++i) ml = max(ml, s_len[i]);

  _Float16* hx = HX + (size_t)g * 8192;       // [parity][chain(16)][unit(256)]
  int* cnt = CNT + g * 16;                    // 64B-padded counter slot
  float h32r[4] = {0.f, 0.f, 0.f, 0.f};       // fp32 master h for (chain lm, units u0..u0+3)

  // prefetch x(0): embed[tok][lq*8 .. +8) per kc chunk
  f16x8 xf[4];
  {
    int p = dir ? (len_l - 1) : 0;
    p = min(max(p, 0), T_ - 1);
    int tok = seqs[(size_t)rowb * T_ + p];
    const float* er = embed + (size_t)tok * E_ + lq * 8;
    #pragma unroll
    for (int kc = 0; kc < 4; ++kc)
      xf[kc] = cvt8(*(const float4*)(er + kc * 32), *(const float4*)(er + kc * 32 + 4));
  }

  for (int t = 0; t < ml; ++t) {
    // poll: all 16 waves completed step t-1 (acquire -> vmcnt drain + L1 invalidate)
    while (__hip_atomic_load(cnt, __ATOMIC_ACQUIRE, __HIP_MEMORY_SCOPE_AGENT) < 16 * t) {}

    // issue x(t+1) gather now (after poll so the acquire doesn't drain it; converted at step end)
    float4 xa0, xb0, xa1, xb1, xa2, xb2, xa3, xb3;
    {
      int p = dir ? (len_l - 2 - t) : (t + 1);
      p = min(max(p, 0), T_ - 1);
      int tok = seqs[(size_t)rowb * T_ + p];
      const float* er = embed + (size_t)tok * E_ + lq * 8;
      xa0 = *(const float4*)(er);      xb0 = *(const float4*)(er + 4);
      xa1 = *(const float4*)(er + 32); xb1 = *(const float4*)(er + 36);
      xa2 = *(const float4*)(er + 64); xb2 = *(const float4*)(er + 68);
      xa3 = *(const float4*)(er + 96); xb3 = *(const float4*)(er + 100);
    }

    // h(t) B-frags: plain loads (L1-reusable; freshness via acquire above)
    const _Float16* hb = hx + (t & 1) * 4096 + lm * 256 + lq * 8;
    f16x8 hf[8];
    #pragma unroll
    for (int kc = 0; kc < 8; ++kc) hf[kc] = *(const f16x8*)(hb + kc * 32);

    f32x4 ar = {}, az = {}, anh = {}, anx = {};
    // x part (weights from LDS, x(t) frags already in regs)
    #pragma unroll
    for (int kc = 0; kc < 4; ++kc) {
      f16x8 wr = *(const f16x8*)(&wlds[w][kc][lane][0]);
      f16x8 wz = *(const f16x8*)(&wlds[w][4 + kc][lane][0]);
      f16x8 wn = *(const f16x8*)(&wlds[w][8 + kc][lane][0]);
      ar  = __builtin_amdgcn_mfma_f32_16x16x32_f16(wr, xf[kc], ar,  0, 0, 0);
      az  = __builtin_amdgcn_mfma_f32_16x16x32_f16(wz, xf[kc], az,  0, 0, 0);
      anx = __builtin_amdgcn_mfma_f32_16x16x32_f16(wn, xf[kc], anx, 0, 0, 0);
    }
    // h part (register weights)
    #pragma unroll
    for (int kc = 0; kc < 8; ++kc) {
      ar  = __builtin_amdgcn_mfma_f32_16x16x32_f16(wh_r[kc], hf[kc], ar,  0, 0, 0);
      az  = __builtin_amdgcn_mfma_f32_16x16x32_f16(wh_z[kc], hf[kc], az,  0, 0, 0);
      anh = __builtin_amdgcn_mfma_f32_16x16x32_f16(wh_n[kc], hf[kc], anh, 0, 0, 0);
    }

    // epilogue: lane holds (chain lm, units u0+i)
    union { f16x4 h4; unsigned long long q; } pk;
    #pragma unroll
    for (int i = 0; i < 4; ++i) {
      float r = sigm(ar[i] + br_[i]);
      float z = sigm(az[i] + bz_[i]);
      float n = tanh_(anx[i] + bx_[i] + r * (anh[i] + bh_[i]));
      float hn = (t < len_l) ? ((1.f - z) * n + z * h32r[i]) : h32r[i];  // freeze past len
      h32r[i] = hn;
      pk.h4[i] = (_Float16)hn;
    }
    // store h(t+1) slice (8 B contiguous, bypasses L1 via agent scope)
    __hip_atomic_store((unsigned long long*)(hx + ((t + 1) & 1) * 4096 + lm * 256 + u0), pk.q,
                       __ATOMIC_RELAXED, __HIP_MEMORY_SCOPE_AGENT);
    // release-add: waits vmcnt(0) (all this wave's loads of h(t) + stores of h(t+1))
    if (lane == 0)
      __hip_atomic_fetch_add(cnt, 1, __ATOMIC_RELEASE, __HIP_MEMORY_SCOPE_AGENT);
    // convert x(t+1) (loads have had the whole step; drained by the release anyway)
    xf[0] = cvt8(xa0, xb0); xf[1] = cvt8(xa1, xb1);
    xf[2] = cvt8(xa2, xb2); xf[3] = cvt8(xa3, xb3);
  }

  // final hidden: lane writes float4 (units u0..u0+3) of chain lm
  float4 o; o.x = h32r[0]; o.y = h32r[1]; o.z = h32r[2]; o.w = h32r[3];
  *(float4*)(&hcat[(size_t)rowb * (2 * H_) + dir * H_ + u0]) = o;
}

// ---------------- final FC: out[b][c] = hcat[b] . W_fc[c] + b_fc[c] ----------------
__global__ __launch_bounds__(512) void fc_kernel(
    const float* __restrict__ hcat, const float* __restrict__ wfc,
    const float* __restrict__ bfc, float* __restrict__ out)
{
  const int b = blockIdx.x, t = threadIdx.x;
  float h  = hcat[(size_t)b * 512 + t];
  float p0 = h * wfc[t];
  float p1 = h * wfc[512 + t];
  #pragma unroll
  for (int off = 32; off > 0; off >>= 1) {
    p0 += __shfl_down(p0, off);
    p1 += __shfl_down(p1, off);
  }
  __shared__ float s0[8], s1[8];
  if ((t & 63) == 0) { s0[t >> 6] = p0; s1[t >> 6] = p1; }
  __syncthreads();
  if (t == 0) {
    float a = bfc[0], c = bfc[1];
    #pragma unroll
    for (int i = 0; i < 8; ++i) { a += s0[i]; c += s1[i]; }
    out[b * 2 + 0] = a;
    out[b * 2 + 1] = c;
  }
}

extern "C" void kernel_launch(void* const* d_in, const int* in_sizes, int n_in,
                              void* d_out, int out_size, void* d_ws, size_t ws_size,
                              hipStream_t stream)
{
  (void)in_sizes; (void)n_in; (void)out_size; (void)ws_size;
  const int*   seqs  = (const int*)d_in[0];
  const int*   lens  = (const int*)d_in[1];
  const float* embed = (const float*)d_in[2];
  const float* wihf  = (const float*)d_in[3];
  const float* whhf  = (const float*)d_in[4];
  const float* bihf  = (const float*)d_in[5];
  const float* bhhf  = (const float*)d_in[6];
  const float* wihb  = (const float*)d_in[7];
  const float* whhb  = (const float*)d_in[8];
  const float* bihb  = (const float*)d_in[9];
  const float* bhhb  = (const float*)d_in[10];
  const float* wfc   = (const float*)d_in[11];
  const float* bfc   = (const float*)d_in[12];
  float* out = (float*)d_out;

  // workspace layout (~2.24 MB)
  char* ws = (char*)d_ws;
  _Float16* WSW = (_Float16*)ws;                         // 1,179,648 B
  size_t off = 1179648;
  float* BIAS = (float*)(ws + off);  off += 8192;
  float* HCAT = (float*)(ws + off);  off += (size_t)B_ * 2 * H_ * 4;   // 524,288
  int* ORDER  = (int*)(ws + off);    off += 1024;
  int* CNT    = (int*)(ws + off);    off += 4096;        // 32 counters, 64 B apart
  _Float16* HX = (_Float16*)(ws + off);                  // 32 groups x 16 KB = 524,288 B

  prep_kernel<<<808, 256, 0, stream>>>(whhf, whhb, wihf, wihb,
                                       bihf, bhhf, bihb, bhhb, WSW, BIAS,
                                       (unsigned int*)HX);
  sort_kernel<<<1, 256, 0, stream>>>(lens, ORDER, CNT);
  scan_kernel<<<64, 512, 0, stream>>>(WSW, BIAS, seqs, embed, lens, ORDER,
                                      HX, CNT, HCAT);
  fc_kernel<<<B_, 512, 0, stream>>>(HCAT, wfc, bfc, out);
}

// Round 6
// 2061.301 us; speedup vs baseline: 2.8178x; 2.8178x over previous
//
#include <hip/hip_runtime.h>
#include <cstdint>
#include <cstddef>

#define B_   256
#define T_   512
#define E_   128
#define H_   256

typedef _Float16 f16x8 __attribute__((ext_vector_type(8)));
typedef _Float16 f16x4 __attribute__((ext_vector_type(4)));
typedef float    f32x4 __attribute__((ext_vector_type(4)));

__device__ __forceinline__ float sigm(float x) { return 1.f / (1.f + __expf(-x)); }
__device__ __forceinline__ float tanh_(float x) {
  x = fminf(15.f, fmaxf(-15.f, x));
  float e = __expf(2.f * x);
  return (e - 1.f) / (e + 1.f);
}
__device__ __forceinline__ void poll_ge(const int* p, int v) {
  while (__hip_atomic_load(p, __ATOMIC_ACQUIRE, __HIP_MEMORY_SCOPE_AGENT) < v)
    __builtin_amdgcn_s_sleep(4);
}

// ---------------- prep: swizzle weights to MFMA fragment order (fp16) -----------------------
// WSW[dir][kc(12)][tile(48)][lane(64)][8] fp16. kc 0..7: W_hh (K=256), kc 8..11: W_ih (K=128).
// Fragment: lane l supplies W[tile*16+(l&15)][k=(l>>4)*8+j] (8 k-consecutive of row-major W).
// Tiles 0..15 = r rows, 16..31 = z, 32..47 = n.  (verified layout, R2/R4/R5 passed)
__global__ __launch_bounds__(256) void prep_kernel(
    const float* __restrict__ whhf, const float* __restrict__ whhb,
    const float* __restrict__ wihf, const float* __restrict__ wihb,
    _Float16* __restrict__ WSW)
{
  int idx = blockIdx.x * 256 + threadIdx.x;   // 288 blocks -> 73728 exactly
  int lane = idx & 63;
  int tile = (idx >> 6) % 48;
  int kc   = (idx / 3072) % 12;
  int dir  = idx / 36864;
  int ncol = tile * 16 + (lane & 15);
  int quad = lane >> 4;
  const float* src;
  if (kc < 8) {
    const float* w = dir ? whhb : whhf;       // [768][256] row-major
    src = w + (size_t)ncol * H_ + kc * 32 + quad * 8;
  } else {
    const float* w = dir ? wihb : wihf;       // [768][128] row-major
    src = w + (size_t)ncol * E_ + (kc - 8) * 32 + quad * 8;
  }
  f16x8 v;
  #pragma unroll
  for (int j = 0; j < 8; ++j) v[j] = (_Float16)src[j];
  *(f16x8*)(WSW + (size_t)idx * 8) = v;
}

// ------- rank rows by length (desc) + init flags (ws is re-poisoned each call) --------------
// FLAGS: [0..1023]  ready slots (g*32 + half*16), init 0
//        [1024..1535] done slots (1024 + g*16),   init -1
__global__ void sort_kernel(const int* __restrict__ lens, int* __restrict__ order,
                            int* __restrict__ flags)
{
  int i = threadIdx.x;                        // one block of 256
  for (int k = i; k < 1024; k += 256) flags[k] = 0;
  for (int k = i; k < 512;  k += 256) flags[1024 + k] = -1;
  int li = lens[i];
  int rank = 0;
  for (int k = 0; k < B_; ++k) {
    int lk = lens[k];
    rank += (lk > li) || (lk == li && k < i);
  }
  order[rank] = i;
}

// ---------------- fused scan + xp producers, 96 blocks ---------------------------------------
// blocks 0..31: consumers. g = bid: dir=g&1, grp=g>>1. One block owns the ENTIRE direction-
//   group recurrence: 16 chains x 256 units. h-weights: 48 frag-tiles/wave (40 in VGPR, n-th1
//   tile-set in LDS). h state in LDS double buffer. ONE __syncthreads per step. Gates:
//   acc = Whh-frags x h-frags (operand swap: D row = unit-in-tile, col = chain; verified R5).
//   xp (= W_ih x + b_ih [+ b_hh for r,z]) read per lane (6x8B) from producer slabs, prefetched
//   one step ahead; chunk boundary (every 16 steps): tid0 release-stores done, acquire-polls
//   both producer ready flags (buffer_inv refreshes L1/L2), barrier.
// blocks 32..95: producers, 2 per g (half=0/1 -> s_local half*8..+8). Chunk c: stage x for 4 s
//   (gather embed, fp32->fp16, LDS B-frags), then 48 tiles x (4 A-frag loads + 16 MFMA), store
//   xp f16x4 in consumer-lane order. Ping-pong buf c&1; overwrite guarded by done >= c-2.
#define XPSLAB 196608        // halfs per (buf,g): 16 s x 12288
__global__ __launch_bounds__(512, 2) void fused_kernel(
    const _Float16* __restrict__ WSW, const int* __restrict__ seqs,
    const float* __restrict__ embed,
    const float* __restrict__ bihf, const float* __restrict__ bhhf,
    const float* __restrict__ bihb, const float* __restrict__ bhhb,
    const int* __restrict__ lens, const int* __restrict__ order,
    _Float16* __restrict__ XP, int* __restrict__ FLAGS, float* __restrict__ hcat)
{
  __shared__ __align__(16) _Float16 wlds[8][8][64][8];   // consumer: n-th1 weight frags, 64 KB
  __shared__ __align__(16) _Float16 hbuf[2][16][264];    // consumer: h state (+8 pad, 16B rows)
  __shared__ __align__(16) _Float16 xstage[4][16][136];  // producer: x B-frag staging
  __shared__ int s_row[16], s_len[16];

  const int bid = blockIdx.x, tid = threadIdx.x;
  const int w = tid >> 6, lane = tid & 63, lm = lane & 15, lq = lane >> 4;

  if (bid < 32) {
    // ================= CONSUMER =================
    const int g = bid, dir = g & 1, grp = g >> 1;
    if (tid < 16) { int r = order[grp * 16 + tid]; s_row[tid] = r; s_len[tid] = lens[r]; }
    for (int i = tid; i < 2 * 16 * 264; i += 512) ((_Float16*)hbuf)[i] = (_Float16)0.f;

    const _Float16* wsd = WSW + (size_t)dir * 294912 + (size_t)lane * 8;
    // LDS tile-set: n-gate th=1 (tile 33+2w). Own-wave write/read.
    #pragma unroll
    for (int kc = 0; kc < 8; ++kc)
      *(f16x8*)(&wlds[w][kc][lane][0]) =
          *(const f16x8*)(wsd + (size_t)kc * 24576 + (33 + 2 * w) * 512);
    // VGPR tile-sets: {2w, 2w+1} = r, {16+2w, 17+2w} = z, {32+2w} = n-th0
    f16x8 wh[5][8];
    #pragma unroll
    for (int kc = 0; kc < 8; ++kc) {
      wh[0][kc] = *(const f16x8*)(wsd + (size_t)kc * 24576 + (2 * w)      * 512);
      wh[1][kc] = *(const f16x8*)(wsd + (size_t)kc * 24576 + (2 * w + 1)  * 512);
      wh[2][kc] = *(const f16x8*)(wsd + (size_t)kc * 24576 + (16 + 2 * w) * 512);
      wh[3][kc] = *(const f16x8*)(wsd + (size_t)kc * 24576 + (17 + 2 * w) * 512);
      wh[4][kc] = *(const f16x8*)(wsd + (size_t)kc * 24576 + (32 + 2 * w) * 512);
    }
    const float* bhh = dir ? bhhb : bhhf;
    float bhn[2][4];
    #pragma unroll
    for (int th = 0; th < 2; ++th) {
      float4 b = *(const float4*)(bhh + 512 + 32 * w + th * 16 + lq * 4);
      bhn[th][0] = b.x; bhn[th][1] = b.y; bhn[th][2] = b.z; bhn[th][3] = b.w;
    }
    __syncthreads();
    const int len_l = s_len[lm], rowb = s_row[lm];
    int ml = 1;
    #pragma unroll
    for (int i = 0; i < 16; ++i) ml = max(ml, s_len[i]);

    int* doneP  = FLAGS + 1024 + g * 16;
    const int* readyA = FLAGS + g * 32;
    const int* readyB = FLAGS + g * 32 + 16;
    float h32r[2][4] = {};
    f16x4 xpn[6];

    for (int t = 0; t < ml; ++t) {
      if ((t & 15) == 0) {                     // chunk boundary
        if (tid == 0) {
          if (t) __hip_atomic_store(doneP, (t >> 4) - 1,
                                    __ATOMIC_RELEASE, __HIP_MEMORY_SCOPE_AGENT);
          poll_ge(readyA, (t >> 4) + 1);
          poll_ge(readyB, (t >> 4) + 1);
        }
        __syncthreads();                       // all waves see fresh caches after tid0 acquire
        const _Float16* sb = XP + ((size_t)((((t >> 4) & 1) * 32 + g)) * 16 + (t & 15)) * 12288
                             + lq * 64 + lm * 4;
        xpn[0] = *(const f16x4*)(sb + (2 * w)      * 256);
        xpn[1] = *(const f16x4*)(sb + (2 * w + 1)  * 256);
        xpn[2] = *(const f16x4*)(sb + (16 + 2 * w) * 256);
        xpn[3] = *(const f16x4*)(sb + (17 + 2 * w) * 256);
        xpn[4] = *(const f16x4*)(sb + (32 + 2 * w) * 256);
        xpn[5] = *(const f16x4*)(sb + (33 + 2 * w) * 256);
      }
      f16x4 xpc[6];
      #pragma unroll
      for (int j = 0; j < 6; ++j) xpc[j] = xpn[j];
      int t1 = t + 1;
      if (t1 < ml && (t1 & 15) != 0) {         // prefetch next step's xp (same chunk)
        const _Float16* sb = XP + ((size_t)((((t1 >> 4) & 1) * 32 + g)) * 16 + (t1 & 15)) * 12288
                             + lq * 64 + lm * 4;
        xpn[0] = *(const f16x4*)(sb + (2 * w)      * 256);
        xpn[1] = *(const f16x4*)(sb + (2 * w + 1)  * 256);
        xpn[2] = *(const f16x4*)(sb + (16 + 2 * w) * 256);
        xpn[3] = *(const f16x4*)(sb + (17 + 2 * w) * 256);
        xpn[4] = *(const f16x4*)(sb + (32 + 2 * w) * 256);
        xpn[5] = *(const f16x4*)(sb + (33 + 2 * w) * 256);
      }

      f32x4 acc[6] = {};
      #pragma unroll
      for (int kc = 0; kc < 8; ++kc) {
        f16x8 hf = *(const f16x8*)(&hbuf[t & 1][lm][kc * 32 + lq * 8]);
        acc[0] = __builtin_amdgcn_mfma_f32_16x16x32_f16(wh[0][kc], hf, acc[0], 0, 0, 0);
        acc[1] = __builtin_amdgcn_mfma_f32_16x16x32_f16(wh[1][kc], hf, acc[1], 0, 0, 0);
        acc[2] = __builtin_amdgcn_mfma_f32_16x16x32_f16(wh[2][kc], hf, acc[2], 0, 0, 0);
        acc[3] = __builtin_amdgcn_mfma_f32_16x16x32_f16(wh[3][kc], hf, acc[3], 0, 0, 0);
        acc[4] = __builtin_amdgcn_mfma_f32_16x16x32_f16(wh[4][kc], hf, acc[4], 0, 0, 0);
        f16x8 w5 = *(const f16x8*)(&wlds[w][kc][lane][0]);
        acc[5] = __builtin_amdgcn_mfma_f32_16x16x32_f16(w5, hf, acc[5], 0, 0, 0);
      }
      // epilogue: lane = (chain lm, units 32w + th*16 + lq*4 + i). r,z biases folded into xp.
      #pragma unroll
      for (int th = 0; th < 2; ++th) {
        union { f16x4 h4; unsigned long long q; } pk;
        #pragma unroll
        for (int i = 0; i < 4; ++i) {
          float r = sigm((float)xpc[th][i]     + acc[th][i]);
          float z = sigm((float)xpc[2 + th][i] + acc[2 + th][i]);
          float n = tanh_((float)xpc[4 + th][i] + r * (acc[4 + th][i] + bhn[th][i]));
          float hn = (t < len_l) ? ((1.f - z) * n + z * h32r[th][i]) : h32r[th][i];
          h32r[th][i] = hn;
          pk.h4[i] = (_Float16)hn;
        }
        *(f16x4*)(&hbuf[(t + 1) & 1][lm][32 * w + th * 16 + lq * 4]) = pk.h4;
      }
      __syncthreads();                         // h(t+1) visible; only barrier per step
    }
    if (tid == 0)
      __hip_atomic_store(doneP, 999, __ATOMIC_RELEASE, __HIP_MEMORY_SCOPE_AGENT);
    #pragma unroll
    for (int th = 0; th < 2; ++th) {
      float4 o; o.x = h32r[th][0]; o.y = h32r[th][1]; o.z = h32r[th][2]; o.w = h32r[th][3];
      *(float4*)(&hcat[(size_t)rowb * (2 * H_) + dir * H_ + 32 * w + th * 16 + lq * 4]) = o;
    }
  } else {
    // ================= PRODUCER =================
    const int pb = bid - 32, g = pb >> 1, half = pb & 1;
    const int dir = g & 1, grp = g >> 1;
    if (tid < 16) { int r = order[grp * 16 + tid]; s_row[tid] = r; s_len[tid] = lens[r]; }
    __syncthreads();
    int ml = 1;
    #pragma unroll
    for (int i = 0; i < 16; ++i) ml = max(ml, s_len[i]);
    const int nch = (ml + 15) >> 4;

    const int chain = tid >> 5, q = tid & 31;  // x-staging: 32 threads/chain
    const int rowb = s_row[chain], lenr = s_len[chain];
    const _Float16* wsd = WSW + (size_t)dir * 294912 + (size_t)lane * 8;
    const float* bih = dir ? bihb : bihf;
    const float* bhh = dir ? bhhb : bhhf;
    const int* doneP = FLAGS + 1024 + g * 16;
    int* readyP = FLAGS + g * 32 + half * 16;

    for (int c = 0; c < nch; ++c) {
      if (c >= 2) { if (tid == 0) poll_ge(doneP, c - 2); __syncthreads(); }
      _Float16* slab = XP + (size_t)((c & 1) * 32 + g) * XPSLAB;
      #pragma unroll
      for (int batch = 0; batch < 2; ++batch) {
        #pragma unroll
        for (int sb = 0; sb < 4; ++sb) {       // stage x for 4 s-values
          int s = c * 16 + half * 8 + batch * 4 + sb;
          int p = dir ? (lenr - 1 - s) : s;
          p = min(max(p, 0), T_ - 1);
          int tok = seqs[(size_t)rowb * T_ + p];
          float4 f = *(const float4*)(embed + (size_t)tok * E_ + q * 4);
          f16x4 h4; h4[0] = (_Float16)f.x; h4[1] = (_Float16)f.y;
          h4[2] = (_Float16)f.z; h4[3] = (_Float16)f.w;
          *(f16x4*)(&xstage[sb][chain][q * 4]) = h4;
        }
        __syncthreads();
        f16x8 bx[4][4];
        #pragma unroll
        for (int sb = 0; sb < 4; ++sb)
          #pragma unroll
          for (int kc = 0; kc < 4; ++kc)
            bx[sb][kc] = *(const f16x8*)(&xstage[sb][lm][kc * 32 + lq * 8]);
        for (int tile = 0; tile < 48; ++tile) {
          f16x8 wA[4];
          #pragma unroll
          for (int kc = 0; kc < 4; ++kc)
            wA[kc] = *(const f16x8*)(wsd + (size_t)(8 + kc) * 24576 + tile * 512);
          float4 bias = *(const float4*)(bih + tile * 16 + lq * 4);
          if (tile < 32) {                     // fold b_hh into r,z xp (n stays separate)
            float4 b2 = *(const float4*)(bhh + tile * 16 + lq * 4);
            bias.x += b2.x; bias.y += b2.y; bias.z += b2.z; bias.w += b2.w;
          }
          f32x4 acc[4] = {};
          #pragma unroll
          for (int kc = 0; kc < 4; ++kc) {
            acc[0] = __builtin_amdgcn_mfma_f32_16x16x32_f16(wA[kc], bx[0][kc], acc[0], 0, 0, 0);
            acc[1] = __builtin_amdgcn_mfma_f32_16x16x32_f16(wA[kc], bx[1][kc], acc[1], 0, 0, 0);
            acc[2] = __builtin_amdgcn_mfma_f32_16x16x32_f16(wA[kc], bx[2][kc], acc[2], 0, 0, 0);
            acc[3] = __builtin_amdgcn_mfma_f32_16x16x32_f16(wA[kc], bx[3][kc], acc[3], 0, 0, 0);
          }
          float bb[4] = {bias.x, bias.y, bias.z, bias.w};
          #pragma unroll
          for (int sb = 0; sb < 4; ++sb) {
            int s_local = half * 8 + batch * 4 + sb;
            f16x4 o;
            #pragma unroll
            for (int i = 0; i < 4; ++i) o[i] = (_Float16)(acc[sb][i] + bb[i]);
            *(f16x4*)(slab + (size_t)s_local * 12288 + tile * 256 + lq * 64 + lm * 4) = o;
          }
        }
        __syncthreads();                       // drains stores; xstage reusable
      }
      if (tid == 0)
        __hip_atomic_store(readyP, c + 1, __ATOMIC_RELEASE, __HIP_MEMORY_SCOPE_AGENT);
    }
  }
}

// ---------------- final FC: out[b][c] = hcat[b] . W_fc[c] + b_fc[c] ----------------
__global__ __launch_bounds__(512) void fc_kernel(
    const float* __restrict__ hcat, const float* __restrict__ wfc,
    const float* __restrict__ bfc, float* __restrict__ out)
{
  const int b = blockIdx.x, t = threadIdx.x;
  float h  = hcat[(size_t)b * 512 + t];
  float p0 = h * wfc[t];
  float p1 = h * wfc[512 + t];
  #pragma unroll
  for (int off = 32; off > 0; off >>= 1) {
    p0 += __shfl_down(p0, off);
    p1 += __shfl_down(p1, off);
  }
  __shared__ float s0[8], s1[8];
  if ((t & 63) == 0) { s0[t >> 6] = p0; s1[t >> 6] = p1; }
  __syncthreads();
  if (t == 0) {
    float a = bfc[0], c = bfc[1];
    #pragma unroll
    for (int i = 0; i < 8; ++i) { a += s0[i]; c += s1[i]; }
    out[b * 2 + 0] = a;
    out[b * 2 + 1] = c;
  }
}

extern "C" void kernel_launch(void* const* d_in, const int* in_sizes, int n_in,
                              void* d_out, int out_size, void* d_ws, size_t ws_size,
                              hipStream_t stream)
{
  (void)in_sizes; (void)n_in; (void)out_size; (void)ws_size;
  const int*   seqs  = (const int*)d_in[0];
  const int*   lens  = (const int*)d_in[1];
  const float* embed = (const float*)d_in[2];
  const float* wihf  = (const float*)d_in[3];
  const float* whhf  = (const float*)d_in[4];
  const float* bihf  = (const float*)d_in[5];
  const float* bhhf  = (const float*)d_in[6];
  const float* wihb  = (const float*)d_in[7];
  const float* whhb  = (const float*)d_in[8];
  const float* bihb  = (const float*)d_in[9];
  const float* bhhb  = (const float*)d_in[10];
  const float* wfc   = (const float*)d_in[11];
  const float* bfc   = (const float*)d_in[12];
  float* out = (float*)d_out;

  // workspace layout (~25.6 MB)
  char* ws = (char*)d_ws;
  _Float16* WSW = (_Float16*)ws;                          // 1,179,648 B
  size_t off = 1179648;
  _Float16* XP  = (_Float16*)(ws + off); off += (size_t)2 * 32 * XPSLAB * 2;  // 25,165,824 B
  float* HCAT   = (float*)(ws + off);    off += (size_t)B_ * 2 * H_ * 4;      // 524,288 B
  int* ORDER    = (int*)(ws + off);      off += 1024;
  int* FLAGS    = (int*)(ws + off);      off += 6144;     // ready[1024] + done[512]

  prep_kernel<<<288, 256, 0, stream>>>(whhf, whhb, wihf, wihb, WSW);
  sort_kernel<<<1, 256, 0, stream>>>(lens, ORDER, FLAGS);
  fused_kernel<<<96, 512, 0, stream>>>(WSW, seqs, embed, bihf, bhhf, bihb, bhhb,
                                       lens, ORDER, XP, FLAGS, HCAT);
  fc_kernel<<<B_, 512, 0, stream>>>(HCAT, wfc, bfc, out);
}

// Round 7
// 1523.951 us; speedup vs baseline: 3.8114x; 1.3526x over previous
//
#include <hip/hip_runtime.h>
#include <cstdint>
#include <cstddef>

#define B_   256
#define T_   512
#define E_   128
#define H_   256

typedef _Float16 f16x8 __attribute__((ext_vector_type(8)));
typedef _Float16 f16x4 __attribute__((ext_vector_type(4)));
typedef float    f32x4 __attribute__((ext_vector_type(4)));

__device__ __forceinline__ float sigm(float x) { return 1.f / (1.f + __expf(-x)); }
__device__ __forceinline__ float tanh_(float x) {
  x = fminf(15.f, fmaxf(-15.f, x));
  float e = __expf(2.f * x);
  return (e - 1.f) / (e + 1.f);
}
__device__ __forceinline__ void poll_ge(const int* p, int v) {
  while (__hip_atomic_load(p, __ATOMIC_ACQUIRE, __HIP_MEMORY_SCOPE_AGENT) < v)
    __builtin_amdgcn_s_sleep(4);
}

// ---------------- prep: swizzle weights to MFMA fragment order (fp16) -----------------------
// WSW[dir][kc(12)][tile(48)][lane(64)][8] fp16. kc 0..7: W_hh (K=256), kc 8..11: W_ih (K=128).
// Fragment: lane l supplies W[tile*16+(l&15)][k=(l>>4)*8+j] (8 k-consecutive of row-major W).
// Tiles 0..15 = r rows, 16..31 = z, 32..47 = n.  (verified layout, R2/R4/R5/R6 passed)
__global__ __launch_bounds__(256) void prep_kernel(
    const float* __restrict__ whhf, const float* __restrict__ whhb,
    const float* __restrict__ wihf, const float* __restrict__ wihb,
    _Float16* __restrict__ WSW)
{
  int idx = blockIdx.x * 256 + threadIdx.x;   // 288 blocks -> 73728 exactly
  int lane = idx & 63;
  int tile = (idx >> 6) % 48;
  int kc   = (idx / 3072) % 12;
  int dir  = idx / 36864;
  int ncol = tile * 16 + (lane & 15);
  int quad = lane >> 4;
  const float* src;
  if (kc < 8) {
    const float* w = dir ? whhb : whhf;       // [768][256] row-major
    src = w + (size_t)ncol * H_ + kc * 32 + quad * 8;
  } else {
    const float* w = dir ? wihb : wihf;       // [768][128] row-major
    src = w + (size_t)ncol * E_ + (kc - 8) * 32 + quad * 8;
  }
  f16x8 v;
  #pragma unroll
  for (int j = 0; j < 8; ++j) v[j] = (_Float16)src[j];
  *(f16x8*)(WSW + (size_t)idx * 8) = v;
}

// ------- rank rows by length (desc) + init flags (ws is re-poisoned each call) --------------
// FLAGS: [0..1023]  ready slots (g*32 + half*16), init 0
//        [1024..1535] done slots (1024 + g*16),   init -1
__global__ void sort_kernel(const int* __restrict__ lens, int* __restrict__ order,
                            int* __restrict__ flags)
{
  int i = threadIdx.x;                        // one block of 256
  for (int k = i; k < 1024; k += 256) flags[k] = 0;
  for (int k = i; k < 512;  k += 256) flags[1024 + k] = -1;
  int li = lens[i];
  int rank = 0;
  for (int k = 0; k < B_; ++k) {
    int lk = lens[k];
    rank += (lk > li) || (lk == li && k < i);
  }
  order[rank] = i;
}

// ---------------- fused scan + xp producers, 96 blocks ---------------------------------------
// blocks 0..31 consumers: one block owns a full direction-group recurrence (16 chains x 256
//   units). Weights per wave: 6 tile-sets; r,z (4 sets) in VGPR (128 regs), n (2 sets) in LDS
//   (16 KB/wave). ONE __syncthreads per step, no in-loop global sync. xp read from producer
//   slabs (prefetched 1 step ahead); chunk boundary every 16 steps: tid0 release done,
//   acquire-poll ready (buffer_inv).
// blocks 32..95 producers (2 per g): chunked xp GEMM, tiles PARTITIONED across waves
//   (R6 bug: all 8 waves computed all 48 tiles). Weights + biases hoisted to registers.
#define XPSLAB 196608        // halfs per (buf,g): 16 s x 12288
__global__ __launch_bounds__(512, 1) void fused_kernel(
    const _Float16* __restrict__ WSW, const int* __restrict__ seqs,
    const float* __restrict__ embed,
    const float* __restrict__ bihf, const float* __restrict__ bhhf,
    const float* __restrict__ bihb, const float* __restrict__ bhhb,
    const int* __restrict__ lens, const int* __restrict__ order,
    _Float16* __restrict__ XP, int* __restrict__ FLAGS, float* __restrict__ hcat)
{
  // one union'd LDS arena:
  // consumer: [0,131072) n-gate weight frags [w][set2][kc8][lane64][8]; [131072,148000) hbuf
  // producer: [0,17408) xstage[4][16][136]
  __shared__ __align__(16) char smem[147968];
  __shared__ int s_row[16], s_len[16];

  const int bid = blockIdx.x, tid = threadIdx.x;
  const int w = tid >> 6, lane = tid & 63, lm = lane & 15, lq = lane >> 4;

  if (bid < 32) {
    // ================= CONSUMER =================
    const int g = bid, dir = g & 1, grp = g >> 1;
    _Float16* wl = (_Float16*)smem;                        // n-gate frags
    _Float16* hb = (_Float16*)(smem + 131072);             // [buf][chain][264]
    if (tid < 16) { int r = order[grp * 16 + tid]; s_row[tid] = r; s_len[tid] = lens[r]; }
    for (int i = tid; i < 2 * 16 * 264; i += 512) hb[i] = (_Float16)0.f;

    const _Float16* wsd = WSW + (size_t)dir * 294912 + (size_t)lane * 8;
    #pragma unroll
    for (int kc = 0; kc < 8; ++kc) {                       // n tiles -> LDS (own-wave region)
      *(f16x8*)(wl + ((w * 2 + 0) * 8 + kc) * 512 + lane * 8) =
          *(const f16x8*)(wsd + (size_t)kc * 24576 + (32 + 2 * w) * 512);
      *(f16x8*)(wl + ((w * 2 + 1) * 8 + kc) * 512 + lane * 8) =
          *(const f16x8*)(wsd + (size_t)kc * 24576 + (33 + 2 * w) * 512);
    }
    f16x8 wh[4][8];                                        // r,z tiles -> VGPR (128 regs)
    #pragma unroll
    for (int kc = 0; kc < 8; ++kc) {
      wh[0][kc] = *(const f16x8*)(wsd + (size_t)kc * 24576 + (2 * w)      * 512);
      wh[1][kc] = *(const f16x8*)(wsd + (size_t)kc * 24576 + (2 * w + 1)  * 512);
      wh[2][kc] = *(const f16x8*)(wsd + (size_t)kc * 24576 + (16 + 2 * w) * 512);
      wh[3][kc] = *(const f16x8*)(wsd + (size_t)kc * 24576 + (17 + 2 * w) * 512);
    }
    const float* bhh = dir ? bhhb : bhhf;
    float bhn[2][4];
    #pragma unroll
    for (int th = 0; th < 2; ++th) {
      float4 b = *(const float4*)(bhh + 512 + 32 * w + th * 16 + lq * 4);
      bhn[th][0] = b.x; bhn[th][1] = b.y; bhn[th][2] = b.z; bhn[th][3] = b.w;
    }
    __syncthreads();
    const int len_l = s_len[lm], rowb = s_row[lm];
    int ml = 1;
    #pragma unroll
    for (int i = 0; i < 16; ++i) ml = max(ml, s_len[i]);

    int* doneP  = FLAGS + 1024 + g * 16;
    const int* readyA = FLAGS + g * 32;
    const int* readyB = FLAGS + g * 32 + 16;
    float h32r[2][4] = {};
    f16x4 xpn[6];

    for (int t = 0; t < ml; ++t) {
      if ((t & 15) == 0) {                     // chunk boundary
        if (tid == 0) {
          if (t) __hip_atomic_store(doneP, (t >> 4) - 1,
                                    __ATOMIC_RELEASE, __HIP_MEMORY_SCOPE_AGENT);
          poll_ge(readyA, (t >> 4) + 1);
          poll_ge(readyB, (t >> 4) + 1);
        }
        __syncthreads();
        const _Float16* sb = XP + ((size_t)((((t >> 4) & 1) * 32 + g)) * 16 + (t & 15)) * 12288
                             + lq * 64 + lm * 4;
        xpn[0] = *(const f16x4*)(sb + (2 * w)      * 256);
        xpn[1] = *(const f16x4*)(sb + (2 * w + 1)  * 256);
        xpn[2] = *(const f16x4*)(sb + (16 + 2 * w) * 256);
        xpn[3] = *(const f16x4*)(sb + (17 + 2 * w) * 256);
        xpn[4] = *(const f16x4*)(sb + (32 + 2 * w) * 256);
        xpn[5] = *(const f16x4*)(sb + (33 + 2 * w) * 256);
      }
      f16x4 xpc[6];
      #pragma unroll
      for (int j = 0; j < 6; ++j) xpc[j] = xpn[j];
      int t1 = t + 1;
      if (t1 < ml && (t1 & 15) != 0) {         // prefetch next step's xp (same chunk)
        const _Float16* sb = XP + ((size_t)((((t1 >> 4) & 1) * 32 + g)) * 16 + (t1 & 15)) * 12288
                             + lq * 64 + lm * 4;
        xpn[0] = *(const f16x4*)(sb + (2 * w)      * 256);
        xpn[1] = *(const f16x4*)(sb + (2 * w + 1)  * 256);
        xpn[2] = *(const f16x4*)(sb + (16 + 2 * w) * 256);
        xpn[3] = *(const f16x4*)(sb + (17 + 2 * w) * 256);
        xpn[4] = *(const f16x4*)(sb + (32 + 2 * w) * 256);
        xpn[5] = *(const f16x4*)(sb + (33 + 2 * w) * 256);
      }

      f32x4 acc[6] = {};
      const _Float16* hrow = hb + ((size_t)(t & 1) * 16 + lm) * 264 + lq * 8;
      #pragma unroll
      for (int kc = 0; kc < 8; ++kc) {
        f16x8 hf = *(const f16x8*)(hrow + kc * 32);
        acc[0] = __builtin_amdgcn_mfma_f32_16x16x32_f16(wh[0][kc], hf, acc[0], 0, 0, 0);
        acc[1] = __builtin_amdgcn_mfma_f32_16x16x32_f16(wh[1][kc], hf, acc[1], 0, 0, 0);
        acc[2] = __builtin_amdgcn_mfma_f32_16x16x32_f16(wh[2][kc], hf, acc[2], 0, 0, 0);
        acc[3] = __builtin_amdgcn_mfma_f32_16x16x32_f16(wh[3][kc], hf, acc[3], 0, 0, 0);
        f16x8 w4 = *(const f16x8*)(wl + ((w * 2 + 0) * 8 + kc) * 512 + lane * 8);
        acc[4] = __builtin_amdgcn_mfma_f32_16x16x32_f16(w4, hf, acc[4], 0, 0, 0);
        f16x8 w5 = *(const f16x8*)(wl + ((w * 2 + 1) * 8 + kc) * 512 + lane * 8);
        acc[5] = __builtin_amdgcn_mfma_f32_16x16x32_f16(w5, hf, acc[5], 0, 0, 0);
      }
      // epilogue: lane = (chain lm, units 32w + th*16 + lq*4 + i). r,z biases folded into xp.
      #pragma unroll
      for (int th = 0; th < 2; ++th) {
        union { f16x4 h4; unsigned long long q; } pk;
        #pragma unroll
        for (int i = 0; i < 4; ++i) {
          float r = sigm((float)xpc[th][i]     + acc[th][i]);
          float z = sigm((float)xpc[2 + th][i] + acc[2 + th][i]);
          float n = tanh_((float)xpc[4 + th][i] + r * (acc[4 + th][i] + bhn[th][i]));
          float hn = (t < len_l) ? ((1.f - z) * n + z * h32r[th][i]) : h32r[th][i];
          h32r[th][i] = hn;
          pk.h4[i] = (_Float16)hn;
        }
        *(f16x4*)(hb + ((size_t)((t + 1) & 1) * 16 + lm) * 264 + 32 * w + th * 16 + lq * 4) = pk.h4;
      }
      __syncthreads();                         // h(t+1) visible; only barrier per step
    }
    if (tid == 0)
      __hip_atomic_store(doneP, 999, __ATOMIC_RELEASE, __HIP_MEMORY_SCOPE_AGENT);
    #pragma unroll
    for (int th = 0; th < 2; ++th) {
      float4 o; o.x = h32r[th][0]; o.y = h32r[th][1]; o.z = h32r[th][2]; o.w = h32r[th][3];
      *(float4*)(&hcat[(size_t)rowb * (2 * H_) + dir * H_ + 32 * w + th * 16 + lq * 4]) = o;
    }
  } else {
    // ================= PRODUCER =================
    const int pb = bid - 32, g = pb >> 1, half = pb & 1;
    const int dir = g & 1, grp = g >> 1;
    _Float16* xs = (_Float16*)smem;                        // [sb4][chain16][136]
    if (tid < 16) { int r = order[grp * 16 + tid]; s_row[tid] = r; s_len[tid] = lens[r]; }
    __syncthreads();
    int ml = 1;
    #pragma unroll
    for (int i = 0; i < 16; ++i) ml = max(ml, s_len[i]);
    const int nch = (ml + 15) >> 4;

    const int chain = tid >> 5, q = tid & 31;  // x-staging: 32 threads/chain
    const int rowb = s_row[chain], lenr = s_len[chain];
    const _Float16* wsd = WSW + (size_t)dir * 294912 + (size_t)lane * 8;
    const float* bih = dir ? bihb : bihf;
    const float* bhh = dir ? bhhb : bhhf;
    const int* doneP = FLAGS + 1024 + g * 16;
    int* readyP = FLAGS + g * 32 + half * 16;

    // hoist this wave's 6 tiles (w, w+8, ..., w+40): weights + biases to registers
    f16x8 wA[6][4];
    float bb[6][4];
    #pragma unroll
    for (int ti = 0; ti < 6; ++ti) {
      const int tile = w + 8 * ti;
      #pragma unroll
      for (int kc = 0; kc < 4; ++kc)
        wA[ti][kc] = *(const f16x8*)(wsd + (size_t)(8 + kc) * 24576 + tile * 512);
      float4 bias = *(const float4*)(bih + tile * 16 + lq * 4);
      if (tile < 32) {                         // fold b_hh into r,z xp (n stays separate)
        float4 b2 = *(const float4*)(bhh + tile * 16 + lq * 4);
        bias.x += b2.x; bias.y += b2.y; bias.z += b2.z; bias.w += b2.w;
      }
      bb[ti][0] = bias.x; bb[ti][1] = bias.y; bb[ti][2] = bias.z; bb[ti][3] = bias.w;
    }

    for (int c = 0; c < nch; ++c) {
      if (c >= 2) { if (tid == 0) poll_ge(doneP, c - 2); __syncthreads(); }
      _Float16* slab = XP + (size_t)((c & 1) * 32 + g) * XPSLAB;
      #pragma unroll
      for (int batch = 0; batch < 2; ++batch) {
        #pragma unroll
        for (int sb = 0; sb < 4; ++sb) {       // stage x for 4 s-values
          int s = c * 16 + half * 8 + batch * 4 + sb;
          int p = dir ? (lenr - 1 - s) : s;
          p = min(max(p, 0), T_ - 1);
          int tok = seqs[(size_t)rowb * T_ + p];
          float4 f = *(const float4*)(embed + (size_t)tok * E_ + q * 4);
          f16x4 h4; h4[0] = (_Float16)f.x; h4[1] = (_Float16)f.y;
          h4[2] = (_Float16)f.z; h4[3] = (_Float16)f.w;
          *(f16x4*)(xs + ((size_t)sb * 16 + chain) * 136 + q * 4) = h4;
        }
        __syncthreads();
        f16x8 bx[4][4];
        #pragma unroll
        for (int sb = 0; sb < 4; ++sb)
          #pragma unroll
          for (int kc = 0; kc < 4; ++kc)
            bx[sb][kc] = *(const f16x8*)(xs + ((size_t)sb * 16 + lm) * 136 + kc * 32 + lq * 8);
        #pragma unroll
        for (int ti = 0; ti < 6; ++ti) {       // tiles partitioned across waves (R6 fix)
          const int tile = w + 8 * ti;
          f32x4 acc[4] = {};
          #pragma unroll
          for (int kc = 0; kc < 4; ++kc) {
            acc[0] = __builtin_amdgcn_mfma_f32_16x16x32_f16(wA[ti][kc], bx[0][kc], acc[0], 0, 0, 0);
            acc[1] = __builtin_amdgcn_mfma_f32_16x16x32_f16(wA[ti][kc], bx[1][kc], acc[1], 0, 0, 0);
            acc[2] = __builtin_amdgcn_mfma_f32_16x16x32_f16(wA[ti][kc], bx[2][kc], acc[2], 0, 0, 0);
            acc[3] = __builtin_amdgcn_mfma_f32_16x16x32_f16(wA[ti][kc], bx[3][kc], acc[3], 0, 0, 0);
          }
          #pragma unroll
          for (int sb = 0; sb < 4; ++sb) {
            int s_local = half * 8 + batch * 4 + sb;
            f16x4 o;
            #pragma unroll
            for (int i = 0; i < 4; ++i) o[i] = (_Float16)(acc[sb][i] + bb[ti][i]);
            *(f16x4*)(slab + (size_t)s_local * 12288 + tile * 256 + lq * 64 + lm * 4) = o;
          }
        }
        __syncthreads();                       // drains; xstage reusable
      }
      if (tid == 0)
        __hip_atomic_store(readyP, c + 1, __ATOMIC_RELEASE, __HIP_MEMORY_SCOPE_AGENT);
    }
  }
}

// ---------------- final FC: out[b][c] = hcat[b] . W_fc[c] + b_fc[c] ----------------
__global__ __launch_bounds__(512) void fc_kernel(
    const float* __restrict__ hcat, const float* __restrict__ wfc,
    const float* __restrict__ bfc, float* __restrict__ out)
{
  const int b = blockIdx.x, t = threadIdx.x;
  float h  = hcat[(size_t)b * 512 + t];
  float p0 = h * wfc[t];
  float p1 = h * wfc[512 + t];
  #pragma unroll
  for (int off = 32; off > 0; off >>= 1) {
    p0 += __shfl_down(p0, off);
    p1 += __shfl_down(p1, off);
  }
  __shared__ float s0[8], s1[8];
  if ((t & 63) == 0) { s0[t >> 6] = p0; s1[t >> 6] = p1; }
  __syncthreads();
  if (t == 0) {
    float a = bfc[0], c = bfc[1];
    #pragma unroll
    for (int i = 0; i < 8; ++i) { a += s0[i]; c += s1[i]; }
    out[b * 2 + 0] = a;
    out[b * 2 + 1] = c;
  }
}

extern "C" void kernel_launch(void* const* d_in, const int* in_sizes, int n_in,
                              void* d_out, int out_size, void* d_ws, size_t ws_size,
                              hipStream_t stream)
{
  (void)in_sizes; (void)n_in; (void)out_size; (void)ws_size;
  const int*   seqs  = (const int*)d_in[0];
  const int*   lens  = (const int*)d_in[1];
  const float* embed = (const float*)d_in[2];
  const float* wihf  = (const float*)d_in[3];
  const float* whhf  = (const float*)d_in[4];
  const float* bihf  = (const float*)d_in[5];
  const float* bhhf  = (const float*)d_in[6];
  const float* wihb  = (const float*)d_in[7];
  const float* whhb  = (const float*)d_in[8];
  const float* bihb  = (const float*)d_in[9];
  const float* bhhb  = (const float*)d_in[10];
  const float* wfc   = (const float*)d_in[11];
  const float* bfc   = (const float*)d_in[12];
  float* out = (float*)d_out;

  // workspace layout (~25.6 MB)
  char* ws = (char*)d_ws;
  _Float16* WSW = (_Float16*)ws;                          // 1,179,648 B
  size_t off = 1179648;
  _Float16* XP  = (_Float16*)(ws + off); off += (size_t)2 * 32 * XPSLAB * 2;  // 25,165,824 B
  float* HCAT   = (float*)(ws + off);    off += (size_t)B_ * 2 * H_ * 4;      // 524,288 B
  int* ORDER    = (int*)(ws + off);      off += 1024;
  int* FLAGS    = (int*)(ws + off);      off += 6144;     // ready[1024] + done[512]

  prep_kernel<<<288, 256, 0, stream>>>(whhf, whhb, wihf, wihb, WSW);
  sort_kernel<<<1, 256, 0, stream>>>(lens, ORDER, FLAGS);
  fused_kernel<<<96, 512, 0, stream>>>(WSW, seqs, embed, bihf, bhhf, bihb, bhhb,
                                       lens, ORDER, XP, FLAGS, HCAT);
  fc_kernel<<<B_, 512, 0, stream>>>(HCAT, wfc, bfc, out);
}